// Round 12
// baseline (89.112 us; speedup 1.0000x reference)
//
#include <hip/hip_runtime.h>

// Problem constants: x [32,64,64,64] f32, embed [64,512] f32.
#define N_VEC 131072
#define D 64
#define K 512
#define GUARD 0.05f      // >= 3.8x the derived 2*eps coarse-error requirement
#define FB_Q 16          // flagged queries per fallback block

typedef __attribute__((ext_vector_type(8))) short bf16x8;  // 8 bf16 = 4 VGPR
typedef __attribute__((ext_vector_type(4))) float f32x4;

static __device__ __forceinline__ short f2bf(float f) {   // RNE
  unsigned u = __builtin_bit_cast(unsigned, f);
  u += 0x7fffu + ((u >> 16) & 1u);
  return (short)(u >> 16);
}
static __device__ __forceinline__ float bf2f(short h) {
  unsigned u = ((unsigned)(unsigned short)h) << 16;
  return __builtin_bit_cast(float, u);
}
static __device__ __forceinline__ void split8(const float4 f0, const float4 f1,
                                              bf16x8& h, bf16x8& m) {
  const float v[8] = {f0.x, f0.y, f0.z, f0.w, f1.x, f1.y, f1.z, f1.w};
#pragma unroll
  for (int j = 0; j < 8; ++j) {
    const short hh = f2bf(v[j]);
    h[j] = hh;
    m[j] = f2bf(v[j] - bf2f(hh));
  }
}

// ---------------------------------------------------------------------------
// Prep (grid 40 x 64):
//   blocks 0-31 (tile b): hi fragments -> FH[b*128 + c*64 + lane],
//                         mid fragments -> FM[same]  (MFMA fragment order).
//   blocks 32-39: et[k][d] fp32 transpose + nrm (fma d ascending, identical
//                 to rounds 1-11) + flag-counter zeroing.
// ---------------------------------------------------------------------------
__global__ __launch_bounds__(64) void vq_prep_kernel(
    const float* __restrict__ embed, float* __restrict__ et,
    float* __restrict__ nrm, bf16x8* __restrict__ FH, bf16x8* __restrict__ FM,
    int* __restrict__ cnt)
{
  const int b = blockIdx.x;
  const int lane = threadIdx.x;
  if (b < 32) {
    const int row = lane & 15;   // code within tile
    const int kg  = lane >> 4;   // dim-group
    const int code = b * 16 + row;
#pragma unroll
    for (int c = 0; c < 2; ++c) {
      bf16x8 h, m;
#pragma unroll
      for (int j = 0; j < 8; ++j) {
        const int d = kg * 8 + c * 32 + j;
        const float e = embed[d * K + code];
        const short hh = f2bf(e);
        h[j] = hh;
        m[j] = f2bf(e - bf2f(hh));
      }
      FH[b * 128 + c * 64 + lane] = h;
      FM[b * 128 + c * 64 + lane] = m;
    }
  } else {
    if (b == 32 && lane == 0) cnt[0] = 0;
    const int code = (b - 32) * 64 + lane;     // 0..511
    float s = 0.f;
#pragma unroll
    for (int d = 0; d < D; ++d) {
      const float e = embed[d * K + code];
      et[code * D + d] = e;
      s = fmaf(e, e, s);
    }
    nrm[code] = s;
  }
}

// Chain assignment identical to r10/r11 (bit-identical scores):
// P: hh(c0), hh(c1), hm(c0);  Q: hm(c1), mh(c0), mh(c1).
#define MFMA12(P0, Q0, P1, Q1, BH0, BM0, BH1, BM1) do {                        \
    P0 = __builtin_amdgcn_mfma_f32_16x16x32_bf16(Ah0c0, BH0, kZero, 0, 0, 0); \
    P1 = __builtin_amdgcn_mfma_f32_16x16x32_bf16(Ah1c0, BH0, kZero, 0, 0, 0); \
    Q0 = __builtin_amdgcn_mfma_f32_16x16x32_bf16(Ah0c1, BM1, kZero, 0, 0, 0); \
    Q1 = __builtin_amdgcn_mfma_f32_16x16x32_bf16(Ah1c1, BM1, kZero, 0, 0, 0); \
    P0 = __builtin_amdgcn_mfma_f32_16x16x32_bf16(Ah0c1, BH1, P0, 0, 0, 0);    \
    P1 = __builtin_amdgcn_mfma_f32_16x16x32_bf16(Ah1c1, BH1, P1, 0, 0, 0);    \
    Q0 = __builtin_amdgcn_mfma_f32_16x16x32_bf16(Am0c0, BH0, Q0, 0, 0, 0);    \
    Q1 = __builtin_amdgcn_mfma_f32_16x16x32_bf16(Am1c0, BH0, Q1, 0, 0, 0);    \
    P0 = __builtin_amdgcn_mfma_f32_16x16x32_bf16(Ah0c0, BM0, P0, 0, 0, 0);    \
    P1 = __builtin_amdgcn_mfma_f32_16x16x32_bf16(Ah1c0, BM0, P1, 0, 0, 0);    \
    Q0 = __builtin_amdgcn_mfma_f32_16x16x32_bf16(Am0c1, BH1, Q0, 0, 0, 0);    \
    Q1 = __builtin_amdgcn_mfma_f32_16x16x32_bf16(Am1c1, BH1, Q1, 0, 0, 0);    \
  } while (0)

#define SCORE4(P0, Q0, P1, Q1, CODE, NV) do {                                  \
    _Pragma("unroll")                                                          \
    for (int r = 0; r < 4; ++r) {                                              \
      const float s0 = fmaf(-2.f, P0[r], fmaf(-2.f, Q0[r], (NV)));             \
      b2[r] = __builtin_amdgcn_fmed3f(s0, b1[r], b2[r]);                       \
      if (s0 < b1[r]) { b1[r] = s0; i1[r] = (CODE); }                          \
      const float s1 = fmaf(-2.f, P1[r], fmaf(-2.f, Q1[r], (NV)));             \
      b2[4 + r] = __builtin_amdgcn_fmed3f(s1, b1[4 + r], b2[4 + r]);           \
      if (s1 < b1[4 + r]) { b1[4 + r] = s1; i1[4 + r] = (CODE); }              \
    }                                                                          \
  } while (0)

// ---------------------------------------------------------------------------
// Coarse v6: 512-thread blocks (8 waves, 256 queries). All 512 codes' HI
// fragments staged once into 64 KB LDS (one barrier, none in the loop);
// MID fragments prefetched from L2 one tile ahead. LDS caps occupancy at
// 2 blocks/CU -> launch_bounds(512,4) frees the allocator to 128 VGPRs
// (kills the remat/spill junk of r8-r11). Fused epilogue: per-query winner
// broadcast by shfl, gather q from et (L2-hot), write q + idf, accumulate
// unflagged (q-x)^2 into a deterministic block partial. Score numerics
// bit-identical to r11 (passed); flagged -> exact fallback as before.
// ---------------------------------------------------------------------------
__global__ __launch_bounds__(512, 4) void vq_coarse_kernel(
    const float* __restrict__ x, const bf16x8* __restrict__ FH,
    const bf16x8* __restrict__ FM, const float* __restrict__ nrm,
    const float* __restrict__ et, float* __restrict__ qout,
    float* __restrict__ idf, int* __restrict__ cnt, int* __restrict__ list,
    float* __restrict__ cpart)
{
  __shared__ bf16x8 LBH[4096];   // exactly 64 KB: hi frags, all 32 tiles
  const int tid  = threadIdx.x;
  const int lane = tid & 63;
  const int w    = tid >> 6;     // 0..7
  const int row  = lane & 15;
  const int kg   = lane >> 4;
  const int qbase = blockIdx.x * 256 + w * 32;

  // Stage hi fragments (linear 64 KB copy, 512 thr x 8 x 16 B).
  {
    const float4* src = reinterpret_cast<const float4*>(FH);
    float4* dst = reinterpret_cast<float4*>(LBH);
#pragma unroll
    for (int j = 0; j < 8; ++j) dst[tid + j * 512] = src[tid + j * 512];
  }

  // A fragments (2 query-sets x 2 K-chunks, hi+mid) — bytes identical r5-r11.
  bf16x8 Ah0c0, Ah0c1, Ah1c0, Ah1c1, Am0c0, Am0c1, Am1c0, Am1c1;
  {
    const float* xr0 = x + (size_t)(qbase + row) * D + kg * 8;
    const float* xr1 = x + (size_t)(qbase + 16 + row) * D + kg * 8;
    split8(*reinterpret_cast<const float4*>(xr0),
           *reinterpret_cast<const float4*>(xr0 + 4), Ah0c0, Am0c0);
    split8(*reinterpret_cast<const float4*>(xr0 + 32),
           *reinterpret_cast<const float4*>(xr0 + 36), Ah0c1, Am0c1);
    split8(*reinterpret_cast<const float4*>(xr1),
           *reinterpret_cast<const float4*>(xr1 + 4), Ah1c0, Am1c0);
    split8(*reinterpret_cast<const float4*>(xr1 + 32),
           *reinterpret_cast<const float4*>(xr1 + 36), Ah1c1, Am1c1);
  }
  __syncthreads();   // LDS hi tiles visible to all waves

  float b1[8], b2[8]; int i1[8];   // [s*4+r]
#pragma unroll
  for (int r = 0; r < 8; ++r) { b1[r] = 3.4e38f; b2[r] = 3.4e38f; i1[r] = 0; }

  const f32x4 kZero = {0.f, 0.f, 0.f, 0.f};
  f32x4 aP0, aQ0, aP1, aQ1;

  const bf16x8* fm = FM + lane;      // mid stream (affine)
  const float*  np = nrm + row;      // norm stream (affine)
  const bf16x8* lb = LBH + lane;     // LDS hi stream (affine)
  bf16x8 Bm0 = fm[0], Bm1 = fm[64]; fm += 128;   // mid tile 0
  float nv = np[0]; np += 16;

#pragma unroll 1
  for (int t = 0; t < 32; ++t) {
    const bf16x8 Bh0 = lb[0];
    const bf16x8 Bh1 = lb[64];
    lb += 128;
    const bf16x8 nBm0 = fm[0];       // mid tile t+1 (pad read at t=31)
    const bf16x8 nBm1 = fm[64];
    fm += 128;
    const float nnv = np[0];         // norm tile t+1 (pad read at t=31)
    np += 16;
    MFMA12(aP0, aQ0, aP1, aQ1, Bh0, Bm0, Bh1, Bm1);
    SCORE4(aP0, aQ0, aP1, aQ1, t * 16 + row, nv);
    Bm0 = nBm0; Bm1 = nBm1; nv = nnv;
  }

  // Butterfly merge across the 16 rows (disjoint code subsets -> exact
  // 1st/2nd of union; cross-row ties -> gap 0 -> flagged -> exact fallback).
#pragma unroll
  for (int m = 1; m < 16; m <<= 1) {
#pragma unroll
    for (int r = 0; r < 8; ++r) {
      const float o1 = __shfl_xor(b1[r], m, 64);
      const int   oi = __shfl_xor(i1[r], m, 64);
      const float o2 = __shfl_xor(b2[r], m, 64);
      if (o1 < b1[r]) { b2[r] = fminf(b1[r], o2); b1[r] = o1; i1[r] = oi; }
      else            { b2[r] = fminf(b2[r], o1); }
    }
  }

  // Id writes + compact flag list (one atomic per wave) — unchanged.
  unsigned m32 = 0;
  if (row == 0) {   // lanes 0,16,32,48: each owns 8 queries (2 sets x 4 regs)
#pragma unroll
    for (int r = 0; r < 8; ++r) {
      const int qoff = (r >> 2) * 16 + kg * 4 + (r & 3);
      idf[qbase + qoff] = (float)i1[r];
      if (b2[r] - b1[r] < GUARD) m32 |= 1u << qoff;
    }
  }
  m32 |= __shfl_xor((int)m32, 16, 64);
  m32 |= __shfl_xor((int)m32, 32, 64);
  if (lane == 0 && m32) {
    int base = atomicAdd(cnt, __popc(m32));
    while (m32) {
      const int b = __ffs(m32) - 1;
      m32 &= m32 - 1;
      list[base++] = qbase + b;
    }
  }

  // Fused gather epilogue: lane = dim. Broadcast each query's winner id and
  // guard-gap from the lane group that owns it; gather q row from et (L2),
  // write q (provisional for flagged; fallback overwrites those), accumulate
  // unflagged squared error.
  float wacc = 0.f;
  const float* xw = x + (size_t)qbase * D;
  float* qw = qout + (size_t)qbase * D;
#pragma unroll
  for (int i = 0; i < 32; ++i) {
    const int s   = i >> 4;
    const int w16 = i & 15;
    const int kq  = w16 >> 2;          // owning kg group
    const int r   = s * 4 + (w16 & 3); // register index (compile-time)
    const int id    = __shfl(i1[r], kq * 16, 64);
    const float gap = __shfl(b2[r] - b1[r], kq * 16, 64);
    const float ev = et[(size_t)id * D + lane];
    const float xv = xw[i * D + lane];
    qw[i * D + lane] = ev;
    const float dd = ev - xv;
    if (gap >= GUARD) wacc = fmaf(dd, dd, wacc);   // wave-uniform predicate
  }
  wacc += __shfl_down(wacc, 32, 64);
  wacc += __shfl_down(wacc, 16, 64);
  wacc += __shfl_down(wacc, 8, 64);
  wacc += __shfl_down(wacc, 4, 64);
  wacc += __shfl_down(wacc, 2, 64);
  wacc += __shfl_down(wacc, 1, 64);
  __syncthreads();                      // all waves done with LBH tiles
  float* sred = reinterpret_cast<float*>(LBH);   // alias spent LDS
  if (lane == 0) sred[w] = wacc;
  __syncthreads();
  if (tid == 0) {
    float t = 0.f;
#pragma unroll
    for (int j = 0; j < 8; ++j) t += sred[j];
    cpart[blockIdx.x] = t;
  }
}

// ---------------------------------------------------------------------------
// Fallback: exact fp32 rescore of flagged queries (numerics bit-identical to
// rounds 1-11 exact path), then fused q-row write + sqerr[q] for each.
// ---------------------------------------------------------------------------
__global__ __launch_bounds__(256) void vq_fallback_kernel(
    const float* __restrict__ x, const float* __restrict__ embed,
    const float* __restrict__ nrm, const float* __restrict__ et,
    const int* __restrict__ cnt, const int* __restrict__ list,
    float* __restrict__ idf, float* __restrict__ qout,
    float* __restrict__ sqerr)
{
  __shared__ float x_lds[FB_Q * D];   // 4 KB
  __shared__ int   s_qidx[FB_Q];
  __shared__ float s_best[4][FB_Q];
  __shared__ int   s_bid[4][FB_Q];
  __shared__ int   s_fbid[FB_Q];
  const int tid  = threadIdx.x;
  const int lane = tid & 63;
  const int wv   = tid >> 6;          // 0..3: codes wv*128 + {lane, lane+64}
  const int n = cnt[0];

  for (int qb = blockIdx.x * FB_Q; qb < n; qb += gridDim.x * FB_Q) {
    __syncthreads();   // previous batch fully consumed before overwrite
    if (tid < FB_Q) {
      const int idx = qb + tid;
      s_qidx[tid] = list[idx < n ? idx : qb];  // pad dup-safe
    }
    __syncthreads();
    {  // stage x rows: 16 q x 16 float4 = 256 loads, 1 per thread
      const int qj = tid >> 4, dq = tid & 15;
      *reinterpret_cast<float4*>(&x_lds[qj * D + dq * 4]) =
          *reinterpret_cast<const float4*>(x + (size_t)s_qidx[qj] * D + dq * 4);
    }
    __syncthreads();

    const int c0 = wv * 128 + lane;
    const int c1 = c0 + 64;
    float a0[FB_Q], a1[FB_Q];
#pragma unroll
    for (int i = 0; i < FB_Q; ++i) { a0[i] = 0.f; a1[i] = 0.f; }

#pragma unroll 4
    for (int ch = 0; ch < 16; ++ch) {   // 4 dims per chunk, d ascending
      const int d0 = ch * 4;
      const float e00 = embed[(d0 + 0) * K + c0];
      const float e01 = embed[(d0 + 0) * K + c1];
      const float e10 = embed[(d0 + 1) * K + c0];
      const float e11 = embed[(d0 + 1) * K + c1];
      const float e20 = embed[(d0 + 2) * K + c0];
      const float e21 = embed[(d0 + 2) * K + c1];
      const float e30 = embed[(d0 + 3) * K + c0];
      const float e31 = embed[(d0 + 3) * K + c1];
#pragma unroll
      for (int i = 0; i < FB_Q; ++i) {
        const float4 xv = *reinterpret_cast<const float4*>(&x_lds[i * D + d0]);
        a0[i] = fmaf(xv.x, e00, a0[i]);
        a0[i] = fmaf(xv.y, e10, a0[i]);
        a0[i] = fmaf(xv.z, e20, a0[i]);
        a0[i] = fmaf(xv.w, e30, a0[i]);
        a1[i] = fmaf(xv.x, e01, a1[i]);
        a1[i] = fmaf(xv.y, e11, a1[i]);
        a1[i] = fmaf(xv.z, e21, a1[i]);
        a1[i] = fmaf(xv.w, e31, a1[i]);
      }
    }

    const float nr0 = nrm[c0], nr1 = nrm[c1];
#pragma unroll
    for (int i = 0; i < FB_Q; ++i) {
      float best; int bid;
      const float s0 = fmaf(-2.f, a0[i], nr0);
      best = s0; bid = c0;                      // c0 < c1, visited first
      const float s1 = fmaf(-2.f, a1[i], nr1);
      if (s1 < best) { best = s1; bid = c1; }
#pragma unroll
      for (int off = 32; off > 0; off >>= 1) {
        const float s2 = __shfl_down(best, off, 64);
        const int   b2 = __shfl_down(bid, off, 64);
        if (s2 < best || (s2 == best && b2 < bid)) { best = s2; bid = b2; }
      }
      if (lane == 0) { s_best[wv][i] = best; s_bid[wv][i] = bid; }
    }
    __syncthreads();
    if (tid < FB_Q) {   // merge 4 waves, ascending wv = ascending code range
      float best = s_best[0][tid]; int bid = s_bid[0][tid];
#pragma unroll
      for (int w = 1; w < 4; ++w) {
        const float s = s_best[w][tid];
        if (s < best) { best = s; bid = s_bid[w][tid]; }  // tie keeps lower k
      }
      idf[s_qidx[tid]] = (float)bid;
      s_fbid[tid] = bid;
    }
    __syncthreads();
    // Fused q-row write + exact sqerr for this batch (lane = dim).
#pragma unroll
    for (int i2 = 0; i2 < 4; ++i2) {
      const int slot = wv * 4 + i2;
      const int qq   = s_qidx[slot];
      const int fb   = s_fbid[slot];
      const float ev = et[(size_t)fb * D + lane];
      const float xv = x_lds[slot * D + lane];
      qout[(size_t)qq * D + lane] = ev;
      float dd = (ev - xv) * (ev - xv);
      dd += __shfl_down(dd, 32, 64);
      dd += __shfl_down(dd, 16, 64);
      dd += __shfl_down(dd, 8, 64);
      dd += __shfl_down(dd, 4, 64);
      dd += __shfl_down(dd, 2, 64);
      dd += __shfl_down(dd, 1, 64);
      if (lane == 0) sqerr[qq] = dd;
    }
  }
}

// ---------------------------------------------------------------------------
// Finalize 1: block b sums sqerr[b*256 .. b*256+256) -> fpart[b]. Fixed order.
// ---------------------------------------------------------------------------
__global__ __launch_bounds__(256) void vq_fin1_kernel(
    const float* __restrict__ sqerr, float* __restrict__ fpart)
{
  float v = sqerr[blockIdx.x * 256 + threadIdx.x];
  v += __shfl_down(v, 32, 64);
  v += __shfl_down(v, 16, 64);
  v += __shfl_down(v, 8, 64);
  v += __shfl_down(v, 4, 64);
  v += __shfl_down(v, 2, 64);
  v += __shfl_down(v, 1, 64);
  __shared__ float sred[4];
  if ((threadIdx.x & 63) == 0) sred[threadIdx.x >> 6] = v;
  __syncthreads();
  if (threadIdx.x == 0)
    fpart[blockIdx.x] = (sred[0] + sred[1]) + (sred[2] + sred[3]);
}

// ---------------------------------------------------------------------------
// Finalize 2: diff = (sum(cpart) + sum(fpart)) / (N*D). Fixed order.
// ---------------------------------------------------------------------------
__global__ __launch_bounds__(256) void vq_fin2_kernel(
    const float* __restrict__ cpart, const float* __restrict__ fpart,
    float* __restrict__ out)
{
  const int tid = threadIdx.x;
  float acc = cpart[tid] + cpart[tid + 256] + fpart[tid] + fpart[tid + 256];
  acc += __shfl_down(acc, 32, 64);
  acc += __shfl_down(acc, 16, 64);
  acc += __shfl_down(acc, 8, 64);
  acc += __shfl_down(acc, 4, 64);
  acc += __shfl_down(acc, 2, 64);
  acc += __shfl_down(acc, 1, 64);
  __shared__ float sred[4];
  if ((tid & 63) == 0) sred[tid >> 6] = acc;
  __syncthreads();
  if (tid == 0)
    out[0] = ((sred[0] + sred[1]) + (sred[2] + sred[3])) * (1.0f / (float)(N_VEC * D));
}

extern "C" void kernel_launch(void* const* d_in, const int* in_sizes, int n_in,
                              void* d_out, int out_size, void* d_ws, size_t ws_size,
                              hipStream_t stream) {
  const float* x = (const float*)d_in[0];
  const float* embed = (const float*)d_in[1];
  float* out = (float*)d_out;
  float* q    = out;                 // [0, 8388608): q_st
  float* diff = out + 8388608;       // commitment loss scalar
  float* idf  = out + 8388609;       // emd_id as float [131072]

  float* ws = (float*)d_ws;          // layout (float indices):
  float* et    = ws;                 // [0, 32768)        fp32 codebook rows
  float* nrm   = ws + 32768;         // [32768, 33344)    512 norms + 64 pad
  float* cpart = ws + 33344;         // [33344, 33856)    coarse partials (512)
  float* fpart = ws + 33856;         // [33856, 34368)    fin1 partials (512)
  int*   cnt   = (int*)(ws + 34368); // flag counter (8 floats reserved)
  int*   list  = (int*)(ws + 34376); // flagged query indices [131072]
  bf16x8* FH = (bf16x8*)(ws + 34376 + N_VEC);            // 64 KB hi frags
  bf16x8* FM = (bf16x8*)(ws + 34376 + N_VEC + 16384);    // 64 KB mid + 2KB pad
  float* sqerr = ws + 34376 + N_VEC + 16384 + 16384 + 512;  // [131072]

  hipMemsetAsync(sqerr, 0, N_VEC * sizeof(float), stream);
  vq_prep_kernel<<<40, 64, 0, stream>>>(embed, et, nrm, FH, FM, cnt);
  vq_coarse_kernel<<<512, 512, 0, stream>>>(x, FH, FM, nrm, et, q, idf, cnt,
                                            list, cpart);
  vq_fallback_kernel<<<1024, 256, 0, stream>>>(x, embed, nrm, et, cnt, list,
                                               idf, q, sqerr);
  vq_fin1_kernel<<<512, 256, 0, stream>>>(sqerr, fpart);
  vq_fin2_kernel<<<1, 256, 0, stream>>>(cpart, fpart, diff);
}

// Round 13
// 85.092 us; speedup vs baseline: 1.0472x; 1.0472x over previous
//
#include <hip/hip_runtime.h>

// Problem constants: x [32,64,64,64] f32, embed [64,512] f32.
#define N_VEC 131072
#define K 512
#define D 64
#define GUARD 0.05f      // >= 3.8x the derived 2*eps coarse-error requirement
#define NB_GATHER 2048
#define FB_Q 16          // flagged queries per fallback block

typedef __attribute__((ext_vector_type(8))) short bf16x8;  // 8 bf16 = 4 VGPR
typedef __attribute__((ext_vector_type(4))) float f32x4;

// Force a value into arch VGPRs (empty asm, no code emitted; the register
// allocator must satisfy the "v" class, so MFMA dst coalesced with this
// operand becomes VGPR-form -> no v_accvgpr_read/write churn per tile).
#define PIN(v) asm("" : "+v"(v))

static __device__ __forceinline__ short f2bf(float f) {   // RNE
  unsigned u = __builtin_bit_cast(unsigned, f);
  u += 0x7fffu + ((u >> 16) & 1u);
  return (short)(u >> 16);
}
static __device__ __forceinline__ float bf2f(short h) {
  unsigned u = ((unsigned)(unsigned short)h) << 16;
  return __builtin_bit_cast(float, u);
}
static __device__ __forceinline__ void split8(const float4 f0, const float4 f1,
                                              bf16x8& h, bf16x8& m) {
  const float v[8] = {f0.x, f0.y, f0.z, f0.w, f1.x, f1.y, f1.z, f1.w};
#pragma unroll
  for (int j = 0; j < 8; ++j) {
    const short hh = f2bf(v[j]);
    h[j] = hh;
    m[j] = f2bf(v[j] - bf2f(hh));
  }
}

// ---------------------------------------------------------------------------
// Prep (grid 40 x 64): unchanged (proven r10-r12).
//   blocks 0-31:  pack codebook hi/mid bf16 B-fragments (tile b) into F in
//                 MFMA fragment order: F[t*256 + c*128 + s*64 + lane].
//   blocks 32-39: et[k][d] fp32 transpose + nrm + flag-counter zeroing.
// ---------------------------------------------------------------------------
__global__ __launch_bounds__(64) void vq_prep_kernel(
    const float* __restrict__ embed, float* __restrict__ et,
    float* __restrict__ nrm, bf16x8* __restrict__ F, int* __restrict__ cnt)
{
  const int b = blockIdx.x;
  const int lane = threadIdx.x;
  if (b < 32) {
    const int row = lane & 15;   // code within tile
    const int kg  = lane >> 4;   // dim-group
    const int code = b * 16 + row;
#pragma unroll
    for (int c = 0; c < 2; ++c) {
      bf16x8 h, m;
#pragma unroll
      for (int j = 0; j < 8; ++j) {
        const int d = kg * 8 + c * 32 + j;
        const float e = embed[d * K + code];
        const short hh = f2bf(e);
        h[j] = hh;
        m[j] = f2bf(e - bf2f(hh));
      }
      F[b * 256 + c * 128 + 0  + lane] = h;
      F[b * 256 + c * 128 + 64 + lane] = m;
    }
  } else {
    if (b == 32 && lane == 0) cnt[0] = 0;
    const int code = (b - 32) * 64 + lane;     // 0..511
    float s = 0.f;
#pragma unroll
    for (int d = 0; d < D; ++d) {
      const float e = embed[d * K + code];
      et[code * D + d] = e;
      s = fmaf(e, e, s);
    }
    nrm[code] = s;
  }
}

// Chain assignment identical to r10/r11/r12 (bit-identical scores):
// P: hh(c0), hh(c1), hm(c0);  Q: hm(c1), mh(c0), mh(c1).
#define MFMA12(P0, Q0, P1, Q1, BH0, BM0, BH1, BM1) do {                        \
    P0 = __builtin_amdgcn_mfma_f32_16x16x32_bf16(Ah0c0, BH0, kZero, 0, 0, 0); \
    P1 = __builtin_amdgcn_mfma_f32_16x16x32_bf16(Ah1c0, BH0, kZero, 0, 0, 0); \
    Q0 = __builtin_amdgcn_mfma_f32_16x16x32_bf16(Ah0c1, BM1, kZero, 0, 0, 0); \
    Q1 = __builtin_amdgcn_mfma_f32_16x16x32_bf16(Ah1c1, BM1, kZero, 0, 0, 0); \
    P0 = __builtin_amdgcn_mfma_f32_16x16x32_bf16(Ah0c1, BH1, P0, 0, 0, 0);    \
    P1 = __builtin_amdgcn_mfma_f32_16x16x32_bf16(Ah1c1, BH1, P1, 0, 0, 0);    \
    Q0 = __builtin_amdgcn_mfma_f32_16x16x32_bf16(Am0c0, BH0, Q0, 0, 0, 0);    \
    Q1 = __builtin_amdgcn_mfma_f32_16x16x32_bf16(Am1c0, BH0, Q1, 0, 0, 0);    \
    P0 = __builtin_amdgcn_mfma_f32_16x16x32_bf16(Ah0c0, BM0, P0, 0, 0, 0);    \
    P1 = __builtin_amdgcn_mfma_f32_16x16x32_bf16(Ah1c0, BM0, P1, 0, 0, 0);    \
    Q0 = __builtin_amdgcn_mfma_f32_16x16x32_bf16(Am0c1, BH1, Q0, 0, 0, 0);    \
    Q1 = __builtin_amdgcn_mfma_f32_16x16x32_bf16(Am1c1, BH1, Q1, 0, 0, 0);    \
  } while (0)

#define SCORE4(P0, Q0, P1, Q1, CODE, NV) do {                                  \
    _Pragma("unroll")                                                          \
    for (int r = 0; r < 4; ++r) {                                              \
      const float s0 = fmaf(-2.f, P0[r], fmaf(-2.f, Q0[r], (NV)));             \
      b2[r] = __builtin_amdgcn_fmed3f(s0, b1[r], b2[r]);                       \
      if (s0 < b1[r]) { b1[r] = s0; i1[r] = (CODE); }                          \
      const float s1 = fmaf(-2.f, P1[r], fmaf(-2.f, Q1[r], (NV)));             \
      b2[4 + r] = __builtin_amdgcn_fmed3f(s1, b1[4 + r], b2[4 + r]);           \
      if (s1 < b1[4 + r]) { b1[4 + r] = s1; i1[4 + r] = (CODE); }              \
    }                                                                          \
  } while (0)

// ---------------------------------------------------------------------------
// Coarse v7: r10's simple structure (1 wave/block, 32 queries, L2-direct B
// with 1-tile register prefetch) + accumulator VGPR pins. The ONLY change vs
// r10 is PIN() on the zero C-operand and the 4 per-tile accumulators, which
// forces VGPR-form MFMA and eliminates the per-tile v_accvgpr read/write
// churn (the suspected 2.7x VALU inflation of r8-r12). Score numerics
// bit-identical to r10/r11 (passed).
// ---------------------------------------------------------------------------
__global__ __launch_bounds__(64, 4) void vq_coarse_kernel(
    const float* __restrict__ x, const bf16x8* __restrict__ F,
    const float* __restrict__ nrm, float* __restrict__ idf,
    int* __restrict__ cnt, int* __restrict__ list)
{
  const int lane = threadIdx.x;      // 0..63
  const int wid  = blockIdx.x;
  const int qbase = wid * 32;
  const int row = lane & 15;
  const int kg  = lane >> 4;

  // A fragments (2 query-sets x 2 K-chunks, hi+mid) — bytes identical r5-r12.
  bf16x8 Ah0c0, Ah0c1, Ah1c0, Ah1c1, Am0c0, Am0c1, Am1c0, Am1c1;
  {
    const float* xr0 = x + (size_t)(qbase + row) * D + kg * 8;
    const float* xr1 = x + (size_t)(qbase + 16 + row) * D + kg * 8;
    split8(*reinterpret_cast<const float4*>(xr0),
           *reinterpret_cast<const float4*>(xr0 + 4), Ah0c0, Am0c0);
    split8(*reinterpret_cast<const float4*>(xr0 + 32),
           *reinterpret_cast<const float4*>(xr0 + 36), Ah0c1, Am0c1);
    split8(*reinterpret_cast<const float4*>(xr1),
           *reinterpret_cast<const float4*>(xr1 + 4), Ah1c0, Am1c0);
    split8(*reinterpret_cast<const float4*>(xr1 + 32),
           *reinterpret_cast<const float4*>(xr1 + 36), Ah1c1, Am1c1);
  }

  float b1[8], b2[8]; int i1[8];   // [s*4+r]
#pragma unroll
  for (int r = 0; r < 8; ++r) { b1[r] = 3.4e38f; b2[r] = 3.4e38f; i1[r] = 0; }

  f32x4 kZero = {0.f, 0.f, 0.f, 0.f};
  PIN(kZero);                       // C operand in VGPR -> D (acc) VGPR-form

  // Preload tile 0; affine running pointers.
  const bf16x8* fp = F + lane;
  bf16x8 Bh0 = fp[0], Bm0 = fp[64], Bh1 = fp[128], Bm1 = fp[192];
  fp += 256;
  const float* np = nrm + row;
  float nv = np[0];
  np += 16;

#pragma unroll 1
  for (int t = 0; t < 32; ++t) {
    bf16x8 nh0, nm0, nh1, nm1; float nvn;
    if (t < 31) {                      // issue next-tile loads (L2-hot)
      nh0 = fp[0]; nm0 = fp[64]; nh1 = fp[128]; nm1 = fp[192]; fp += 256;
      nvn = np[0]; np += 16;
    }

    f32x4 p0, q0, p1, q1;
    MFMA12(p0, q0, p1, q1, Bh0, Bm0, Bh1, Bm1);
    PIN(p0); PIN(q0); PIN(p1); PIN(q1);   // accumulators stay in arch VGPRs

    SCORE4(p0, q0, p1, q1, t * 16 + row, nv);
    Bh0 = nh0; Bm0 = nm0; Bh1 = nh1; Bm1 = nm1; nv = nvn;
  }

  // Butterfly merge across the 16 rows (disjoint code subsets -> exact
  // 1st/2nd of union; cross-row ties -> gap 0 -> flagged -> exact fallback).
#pragma unroll
  for (int m = 1; m < 16; m <<= 1) {
#pragma unroll
    for (int r = 0; r < 8; ++r) {
      const float o1 = __shfl_xor(b1[r], m, 64);
      const int   oi = __shfl_xor(i1[r], m, 64);
      const float o2 = __shfl_xor(b2[r], m, 64);
      if (o1 < b1[r]) { b2[r] = fminf(b1[r], o2); b1[r] = o1; i1[r] = oi; }
      else            { b2[r] = fminf(b2[r], o1); }
    }
  }

  // Id writes + compact flag list (one atomic per wave).
  unsigned m32 = 0;
  if (row == 0) {   // lanes 0,16,32,48: each owns 8 queries (2 sets x 4 regs)
#pragma unroll
    for (int r = 0; r < 8; ++r) {
      const int qoff = (r >> 2) * 16 + kg * 4 + (r & 3);
      idf[qbase + qoff] = (float)i1[r];
      if (b2[r] - b1[r] < GUARD) m32 |= 1u << qoff;
    }
  }
  m32 |= __shfl_xor((int)m32, 16, 64);
  m32 |= __shfl_xor((int)m32, 32, 64);
  if (lane == 0 && m32) {
    int base = atomicAdd(cnt, __popc(m32));
    while (m32) {
      const int b = __ffs(m32) - 1;
      m32 &= m32 - 1;
      list[base++] = qbase + b;
    }
  }
}

// ---------------------------------------------------------------------------
// Fallback v3 (unchanged, proven): exact fp32 rescore, 16 flagged queries per
// block; lane = code, coalesced embed [d][K] reads; numerics bit-identical to
// the round-1 exact path.
// ---------------------------------------------------------------------------
__global__ __launch_bounds__(256) void vq_fallback_kernel(
    const float* __restrict__ x, const float* __restrict__ embed,
    const float* __restrict__ nrm, const int* __restrict__ cnt,
    const int* __restrict__ list, float* __restrict__ idf)
{
  __shared__ float x_lds[FB_Q * D];   // 4 KB
  __shared__ int   s_qidx[FB_Q];
  __shared__ float s_best[4][FB_Q];
  __shared__ int   s_bid[4][FB_Q];
  const int tid  = threadIdx.x;
  const int lane = tid & 63;
  const int wv   = tid >> 6;          // 0..3: codes wv*128 + {lane, lane+64}
  const int n = cnt[0];

  for (int qb = blockIdx.x * FB_Q; qb < n; qb += gridDim.x * FB_Q) {
    __syncthreads();   // previous batch's epilogue reads done before overwrite
    if (tid < FB_Q) {
      const int idx = qb + tid;
      s_qidx[tid] = list[idx < n ? idx : qb];  // pad with first-of-batch (dup-safe)
    }
    __syncthreads();
    {  // stage x rows: 16 q x 16 float4 = 256 loads, 1 per thread
      const int qj = tid >> 4, dq = tid & 15;
      *reinterpret_cast<float4*>(&x_lds[qj * D + dq * 4]) =
          *reinterpret_cast<const float4*>(x + (size_t)s_qidx[qj] * D + dq * 4);
    }
    __syncthreads();

    const int c0 = wv * 128 + lane;
    const int c1 = c0 + 64;
    float a0[FB_Q], a1[FB_Q];
#pragma unroll
    for (int i = 0; i < FB_Q; ++i) { a0[i] = 0.f; a1[i] = 0.f; }

#pragma unroll 4
    for (int ch = 0; ch < 16; ++ch) {   // 4 dims per chunk, d ascending
      const int d0 = ch * 4;
      const float e00 = embed[(d0 + 0) * K + c0];
      const float e01 = embed[(d0 + 0) * K + c1];
      const float e10 = embed[(d0 + 1) * K + c0];
      const float e11 = embed[(d0 + 1) * K + c1];
      const float e20 = embed[(d0 + 2) * K + c0];
      const float e21 = embed[(d0 + 2) * K + c1];
      const float e30 = embed[(d0 + 3) * K + c0];
      const float e31 = embed[(d0 + 3) * K + c1];
#pragma unroll
      for (int i = 0; i < FB_Q; ++i) {
        const float4 xv = *reinterpret_cast<const float4*>(&x_lds[i * D + d0]);
        a0[i] = fmaf(xv.x, e00, a0[i]);
        a0[i] = fmaf(xv.y, e10, a0[i]);
        a0[i] = fmaf(xv.z, e20, a0[i]);
        a0[i] = fmaf(xv.w, e30, a0[i]);
        a1[i] = fmaf(xv.x, e01, a1[i]);
        a1[i] = fmaf(xv.y, e11, a1[i]);
        a1[i] = fmaf(xv.z, e21, a1[i]);
        a1[i] = fmaf(xv.w, e31, a1[i]);
      }
    }

    const float nr0 = nrm[c0], nr1 = nrm[c1];
#pragma unroll
    for (int i = 0; i < FB_Q; ++i) {
      float best; int bid;
      const float s0 = fmaf(-2.f, a0[i], nr0);
      best = s0; bid = c0;                      // c0 < c1, visited first
      const float s1 = fmaf(-2.f, a1[i], nr1);
      if (s1 < best) { best = s1; bid = c1; }
#pragma unroll
      for (int off = 32; off > 0; off >>= 1) {
        const float s2 = __shfl_down(best, off, 64);
        const int   b2 = __shfl_down(bid, off, 64);
        if (s2 < best || (s2 == best && b2 < bid)) { best = s2; bid = b2; }
      }
      if (lane == 0) { s_best[wv][i] = best; s_bid[wv][i] = bid; }
    }
    __syncthreads();
    if (tid < FB_Q) {   // merge 4 waves, ascending wv = ascending code range
      float best = s_best[0][tid]; int bid = s_bid[0][tid];
#pragma unroll
      for (int w = 1; w < 4; ++w) {
        const float s = s_best[w][tid];
        if (s < best) { best = s; bid = s_bid[w][tid]; }  // tie keeps lower k
      }
      idf[s_qidx[tid]] = (float)bid;
    }
  }
}

// ---------------------------------------------------------------------------
// Gather: q = et[id] (exact fp32 rows), write q_st, diff partials.
// ---------------------------------------------------------------------------
__global__ __launch_bounds__(256) void vq_gather_kernel(
    const float* __restrict__ x, const float* __restrict__ et,
    const float* __restrict__ idf, float* __restrict__ q,
    float* __restrict__ partial)
{
  const int tid = blockIdx.x * 256 + threadIdx.x;
  const int stride = gridDim.x * 256;
  float acc = 0.f;
  for (int idx = tid; idx < N_VEC * (D / 4); idx += stride) {
    const int v = idx >> 4;
    const int d4 = idx & 15;
    const int id = (int)idf[v];
    const float4 xv = reinterpret_cast<const float4*>(x)[idx];
    const float4 ev = reinterpret_cast<const float4*>(et)[(id << 4) + d4];
    const float e0 = ev.x - xv.x, e1 = ev.y - xv.y, e2 = ev.z - xv.z, e3 = ev.w - xv.w;
    acc += (e0 * e0 + e1 * e1) + (e2 * e2 + e3 * e3);
    reinterpret_cast<float4*>(q)[idx] = ev;
  }
  acc += __shfl_down(acc, 32, 64);
  acc += __shfl_down(acc, 16, 64);
  acc += __shfl_down(acc, 8, 64);
  acc += __shfl_down(acc, 4, 64);
  acc += __shfl_down(acc, 2, 64);
  acc += __shfl_down(acc, 1, 64);
  __shared__ float sred[4];
  if ((threadIdx.x & 63) == 0) sred[threadIdx.x >> 6] = acc;
  __syncthreads();
  if (threadIdx.x == 0)
    partial[blockIdx.x] = (sred[0] + sred[1]) + (sred[2] + sred[3]);
}

__global__ __launch_bounds__(256) void vq_finalize_kernel(
    const float* __restrict__ partial, float* __restrict__ out)
{
  float acc = 0.f;
  for (int i = threadIdx.x; i < NB_GATHER; i += 256) acc += partial[i];
  acc += __shfl_down(acc, 32, 64);
  acc += __shfl_down(acc, 16, 64);
  acc += __shfl_down(acc, 8, 64);
  acc += __shfl_down(acc, 4, 64);
  acc += __shfl_down(acc, 2, 64);
  acc += __shfl_down(acc, 1, 64);
  __shared__ float sred[4];
  if ((threadIdx.x & 63) == 0) sred[threadIdx.x >> 6] = acc;
  __syncthreads();
  if (threadIdx.x == 0)
    out[0] = ((sred[0] + sred[1]) + (sred[2] + sred[3])) * (1.0f / (float)(N_VEC * D));
}

extern "C" void kernel_launch(void* const* d_in, const int* in_sizes, int n_in,
                              void* d_out, int out_size, void* d_ws, size_t ws_size,
                              hipStream_t stream) {
  const float* x = (const float*)d_in[0];
  const float* embed = (const float*)d_in[1];
  float* out = (float*)d_out;
  float* q    = out;                 // [0, 8388608): q_st
  float* diff = out + 8388608;       // commitment loss scalar
  float* idf  = out + 8388609;       // emd_id as float [131072]

  float* ws = (float*)d_ws;          // layout (float idx):
  float* et      = ws;               // [0, 32768)       fp32 codebook rows
  float* nrm     = ws + 32768;       // [32768, 33312)   512 norms + 32 pad
  float* partial = ws + 33312;       // [33312, 35360)   diff partials
  int*   cnt     = (int*)(ws + 35360);         // flag counter
  int*   list    = (int*)(ws + 35368);         // flagged query indices
  bf16x8* F = (bf16x8*)(ws + 35368 + N_VEC);   // 128 KB packed hi/mid B-frags

  vq_prep_kernel<<<40, 64, 0, stream>>>(embed, et, nrm, F, cnt);
  vq_coarse_kernel<<<N_VEC / 32, 64, 0, stream>>>(x, F, nrm, idf, cnt, list);
  vq_fallback_kernel<<<1024, 256, 0, stream>>>(x, embed, nrm, cnt, list, idf);
  vq_gather_kernel<<<NB_GATHER, 256, 0, stream>>>(x, et, idf, q, partial);
  vq_finalize_kernel<<<1, 256, 0, stream>>>(partial, diff);
}

// Round 14
// 80.771 us; speedup vs baseline: 1.1033x; 1.0535x over previous
//
#include <hip/hip_runtime.h>

// Problem constants: x [32,64,64,64] f32, embed [64,512] f32.
#define N_VEC 131072
#define K 512
#define D 64
#define GUARD 0.05f      // >= 3.8x the derived 2*eps coarse-error requirement
#define NB_GATHER 2048
#define FB_Q 16          // flagged queries per fallback block

typedef __attribute__((ext_vector_type(8))) short bf16x8;  // 8 bf16 = 4 VGPR
typedef __attribute__((ext_vector_type(4))) float f32x4;

static __device__ __forceinline__ short f2bf(float f) {   // RNE
  unsigned u = __builtin_bit_cast(unsigned, f);
  u += 0x7fffu + ((u >> 16) & 1u);
  return (short)(u >> 16);
}
static __device__ __forceinline__ float bf2f(short h) {
  unsigned u = ((unsigned)(unsigned short)h) << 16;
  return __builtin_bit_cast(float, u);
}
static __device__ __forceinline__ void split8(const float4 f0, const float4 f1,
                                              bf16x8& h, bf16x8& m) {
  const float v[8] = {f0.x, f0.y, f0.z, f0.w, f1.x, f1.y, f1.z, f1.w};
#pragma unroll
  for (int j = 0; j < 8; ++j) {
    const short hh = f2bf(v[j]);
    h[j] = hh;
    m[j] = f2bf(v[j] - bf2f(hh));
  }
}

// ---------------------------------------------------------------------------
// Prep (grid 40 x 64): unchanged (proven r10-r13).
//   blocks 0-31:  pack codebook hi/mid bf16 B-fragments (tile b) into F in
//                 MFMA fragment order: F[b*256 + c*128 + {0|64} + lane].
//   blocks 32-39: et[k][d] fp32 transpose + nrm + flag-counter zeroing.
// ---------------------------------------------------------------------------
__global__ __launch_bounds__(64) void vq_prep_kernel(
    const float* __restrict__ embed, float* __restrict__ et,
    float* __restrict__ nrm, bf16x8* __restrict__ F, int* __restrict__ cnt)
{
  const int b = blockIdx.x;
  const int lane = threadIdx.x;
  if (b < 32) {
    const int row = lane & 15;   // code within tile
    const int kg  = lane >> 4;   // dim-group
    const int code = b * 16 + row;
#pragma unroll
    for (int c = 0; c < 2; ++c) {
      bf16x8 h, m;
#pragma unroll
      for (int j = 0; j < 8; ++j) {
        const int d = kg * 8 + c * 32 + j;
        const float e = embed[d * K + code];
        const short hh = f2bf(e);
        h[j] = hh;
        m[j] = f2bf(e - bf2f(hh));
      }
      F[b * 256 + c * 128 + 0  + lane] = h;
      F[b * 256 + c * 128 + 64 + lane] = m;
    }
  } else {
    if (b == 32 && lane == 0) cnt[0] = 0;
    const int code = (b - 32) * 64 + lane;     // 0..511
    float s = 0.f;
#pragma unroll
    for (int d = 0; d < D; ++d) {
      const float e = embed[d * K + code];
      et[code * D + d] = e;
      s = fmaf(e, e, s);
    }
    nrm[code] = s;
  }
}

// Chain assignment identical to r10-r13 (bit-identical scores):
// P: hh(c0), hh(c1), hm(c0);  Q: hm(c1), mh(c0), mh(c1).
#define MFMA12(P0, Q0, P1, Q1, BH0, BM0, BH1, BM1) do {                        \
    P0 = __builtin_amdgcn_mfma_f32_16x16x32_bf16(Ah0c0, BH0, kZero, 0, 0, 0); \
    P1 = __builtin_amdgcn_mfma_f32_16x16x32_bf16(Ah1c0, BH0, kZero, 0, 0, 0); \
    Q0 = __builtin_amdgcn_mfma_f32_16x16x32_bf16(Ah0c1, BM1, kZero, 0, 0, 0); \
    Q1 = __builtin_amdgcn_mfma_f32_16x16x32_bf16(Ah1c1, BM1, kZero, 0, 0, 0); \
    P0 = __builtin_amdgcn_mfma_f32_16x16x32_bf16(Ah0c1, BH1, P0, 0, 0, 0);    \
    P1 = __builtin_amdgcn_mfma_f32_16x16x32_bf16(Ah1c1, BH1, P1, 0, 0, 0);    \
    Q0 = __builtin_amdgcn_mfma_f32_16x16x32_bf16(Am0c0, BH0, Q0, 0, 0, 0);    \
    Q1 = __builtin_amdgcn_mfma_f32_16x16x32_bf16(Am1c0, BH0, Q1, 0, 0, 0);    \
    P0 = __builtin_amdgcn_mfma_f32_16x16x32_bf16(Ah0c0, BM0, P0, 0, 0, 0);    \
    P1 = __builtin_amdgcn_mfma_f32_16x16x32_bf16(Ah1c0, BM0, P1, 0, 0, 0);    \
    Q0 = __builtin_amdgcn_mfma_f32_16x16x32_bf16(Am0c1, BH1, Q0, 0, 0, 0);    \
    Q1 = __builtin_amdgcn_mfma_f32_16x16x32_bf16(Am1c1, BH1, Q1, 0, 0, 0);    \
  } while (0)

#define SCORE4(P0, Q0, P1, Q1, CODE, NV) do {                                  \
    _Pragma("unroll")                                                          \
    for (int r = 0; r < 4; ++r) {                                              \
      const float s0 = fmaf(-2.f, P0[r], fmaf(-2.f, Q0[r], (NV)));             \
      b2[r] = __builtin_amdgcn_fmed3f(s0, b1[r], b2[r]);                       \
      if (s0 < b1[r]) { b1[r] = s0; i1[r] = (CODE); }                          \
      const float s1 = fmaf(-2.f, P1[r], fmaf(-2.f, Q1[r], (NV)));             \
      b2[4 + r] = __builtin_amdgcn_fmed3f(s1, b1[4 + r], b2[4 + r]);           \
      if (s1 < b1[4 + r]) { b1[4 + r] = s1; i1[4 + r] = (CODE); }              \
    }                                                                          \
  } while (0)

// ---------------------------------------------------------------------------
// Coarse v8 (m97-style operand path): 512-thread blocks (8 waves, 32 q/wave),
// grid 512, 2 blocks/CU (LDS-capped) = 4 waves/SIMD. Exactly 64 KB static
// LDS holds one 256-code phase (hi+mid, fragment order); 2 phases, barriers
// only at phase boundaries. Tile loop: 4 ds_read_b128 with compile-time
// offsets -> 12 MFMA -> score, unroll-4 so the scheduler overlaps tiles.
// This is the compiler's proven-clean ds_read->MFMA path (m97). Score
// numerics bit-identical to r10-r13 (passed).
// ---------------------------------------------------------------------------
__global__ __launch_bounds__(512, 4) void vq_coarse_kernel(
    const float* __restrict__ x, const bf16x8* __restrict__ F,
    const float* __restrict__ nrm, float* __restrict__ idf,
    int* __restrict__ cnt, int* __restrict__ list)
{
  __shared__ bf16x8 LB[4096];        // exactly 64 KB: one phase (16 tiles)
  const int tid  = threadIdx.x;
  const int lane = tid & 63;
  const int w    = tid >> 6;         // 0..7
  const int row  = lane & 15;
  const int kg   = lane >> 4;
  const int qbase = blockIdx.x * 256 + w * 32;

  // A fragments (2 query-sets x 2 K-chunks, hi+mid) — bytes identical r5-r13.
  bf16x8 Ah0c0, Ah0c1, Ah1c0, Ah1c1, Am0c0, Am0c1, Am1c0, Am1c1;
  {
    const float* xr0 = x + (size_t)(qbase + row) * D + kg * 8;
    const float* xr1 = x + (size_t)(qbase + 16 + row) * D + kg * 8;
    split8(*reinterpret_cast<const float4*>(xr0),
           *reinterpret_cast<const float4*>(xr0 + 4), Ah0c0, Am0c0);
    split8(*reinterpret_cast<const float4*>(xr0 + 32),
           *reinterpret_cast<const float4*>(xr0 + 36), Ah0c1, Am0c1);
    split8(*reinterpret_cast<const float4*>(xr1),
           *reinterpret_cast<const float4*>(xr1 + 4), Ah1c0, Am1c0);
    split8(*reinterpret_cast<const float4*>(xr1 + 32),
           *reinterpret_cast<const float4*>(xr1 + 36), Ah1c1, Am1c1);
  }

  float b1[8], b2[8]; int i1[8];   // [s*4+r]
#pragma unroll
  for (int r = 0; r < 8; ++r) { b1[r] = 3.4e38f; b2[r] = 3.4e38f; i1[r] = 0; }

  const f32x4 kZero = {0.f, 0.f, 0.f, 0.f};

#pragma unroll 1
  for (int ph = 0; ph < 2; ++ph) {
    if (ph) __syncthreads();         // phase-0 readers done before overwrite
    {  // stage one phase: 64 KB, 512 thr x 8 x float4 (linear, coalesced)
      const float4* src = reinterpret_cast<const float4*>(F + ph * 4096);
      float4* dst = reinterpret_cast<float4*>(LB);
#pragma unroll
      for (int j = 0; j < 8; ++j) dst[tid + j * 512] = src[tid + j * 512];
    }
    __syncthreads();

#pragma unroll 4
    for (int t = 0; t < 16; ++t) {
      const bf16x8 Bh0 = LB[t * 256 + lane];         // ds_read_b128, imm offs
      const bf16x8 Bm0 = LB[t * 256 + 64 + lane];
      const bf16x8 Bh1 = LB[t * 256 + 128 + lane];
      const bf16x8 Bm1 = LB[t * 256 + 192 + lane];
      const int code = (ph * 16 + t) * 16 + row;
      const float nv = nrm[code];
      f32x4 p0, q0, p1, q1;
      MFMA12(p0, q0, p1, q1, Bh0, Bm0, Bh1, Bm1);
      SCORE4(p0, q0, p1, q1, code, nv);
    }
  }

  // Butterfly merge across the 16 rows (disjoint code subsets -> exact
  // 1st/2nd of union; cross-row ties -> gap 0 -> flagged -> exact fallback).
#pragma unroll
  for (int m = 1; m < 16; m <<= 1) {
#pragma unroll
    for (int r = 0; r < 8; ++r) {
      const float o1 = __shfl_xor(b1[r], m, 64);
      const int   oi = __shfl_xor(i1[r], m, 64);
      const float o2 = __shfl_xor(b2[r], m, 64);
      if (o1 < b1[r]) { b2[r] = fminf(b1[r], o2); b1[r] = o1; i1[r] = oi; }
      else            { b2[r] = fminf(b2[r], o1); }
    }
  }

  // Id writes + compact flag list (one atomic per wave).
  unsigned m32 = 0;
  if (row == 0) {   // lanes 0,16,32,48: each owns 8 queries (2 sets x 4 regs)
#pragma unroll
    for (int r = 0; r < 8; ++r) {
      const int qoff = (r >> 2) * 16 + kg * 4 + (r & 3);
      idf[qbase + qoff] = (float)i1[r];
      if (b2[r] - b1[r] < GUARD) m32 |= 1u << qoff;
    }
  }
  m32 |= __shfl_xor((int)m32, 16, 64);
  m32 |= __shfl_xor((int)m32, 32, 64);
  if (lane == 0 && m32) {
    int base = atomicAdd(cnt, __popc(m32));
    while (m32) {
      const int b = __ffs(m32) - 1;
      m32 &= m32 - 1;
      list[base++] = qbase + b;
    }
  }
}

// ---------------------------------------------------------------------------
// Fallback v3 (unchanged, proven): exact fp32 rescore, 16 flagged queries per
// block; lane = code, coalesced embed [d][K] reads; numerics bit-identical to
// the round-1 exact path.
// ---------------------------------------------------------------------------
__global__ __launch_bounds__(256) void vq_fallback_kernel(
    const float* __restrict__ x, const float* __restrict__ embed,
    const float* __restrict__ nrm, const int* __restrict__ cnt,
    const int* __restrict__ list, float* __restrict__ idf)
{
  __shared__ float x_lds[FB_Q * D];   // 4 KB
  __shared__ int   s_qidx[FB_Q];
  __shared__ float s_best[4][FB_Q];
  __shared__ int   s_bid[4][FB_Q];
  const int tid  = threadIdx.x;
  const int lane = tid & 63;
  const int wv   = tid >> 6;          // 0..3: codes wv*128 + {lane, lane+64}
  const int n = cnt[0];

  for (int qb = blockIdx.x * FB_Q; qb < n; qb += gridDim.x * FB_Q) {
    __syncthreads();   // previous batch's epilogue reads done before overwrite
    if (tid < FB_Q) {
      const int idx = qb + tid;
      s_qidx[tid] = list[idx < n ? idx : qb];  // pad with first-of-batch (dup-safe)
    }
    __syncthreads();
    {  // stage x rows: 16 q x 16 float4 = 256 loads, 1 per thread
      const int qj = tid >> 4, dq = tid & 15;
      *reinterpret_cast<float4*>(&x_lds[qj * D + dq * 4]) =
          *reinterpret_cast<const float4*>(x + (size_t)s_qidx[qj] * D + dq * 4);
    }
    __syncthreads();

    const int c0 = wv * 128 + lane;
    const int c1 = c0 + 64;
    float a0[FB_Q], a1[FB_Q];
#pragma unroll
    for (int i = 0; i < FB_Q; ++i) { a0[i] = 0.f; a1[i] = 0.f; }

#pragma unroll 4
    for (int ch = 0; ch < 16; ++ch) {   // 4 dims per chunk, d ascending
      const int d0 = ch * 4;
      const float e00 = embed[(d0 + 0) * K + c0];
      const float e01 = embed[(d0 + 0) * K + c1];
      const float e10 = embed[(d0 + 1) * K + c0];
      const float e11 = embed[(d0 + 1) * K + c1];
      const float e20 = embed[(d0 + 2) * K + c0];
      const float e21 = embed[(d0 + 2) * K + c1];
      const float e30 = embed[(d0 + 3) * K + c0];
      const float e31 = embed[(d0 + 3) * K + c1];
#pragma unroll
      for (int i = 0; i < FB_Q; ++i) {
        const float4 xv = *reinterpret_cast<const float4*>(&x_lds[i * D + d0]);
        a0[i] = fmaf(xv.x, e00, a0[i]);
        a0[i] = fmaf(xv.y, e10, a0[i]);
        a0[i] = fmaf(xv.z, e20, a0[i]);
        a0[i] = fmaf(xv.w, e30, a0[i]);
        a1[i] = fmaf(xv.x, e01, a1[i]);
        a1[i] = fmaf(xv.y, e11, a1[i]);
        a1[i] = fmaf(xv.z, e21, a1[i]);
        a1[i] = fmaf(xv.w, e31, a1[i]);
      }
    }

    const float nr0 = nrm[c0], nr1 = nrm[c1];
#pragma unroll
    for (int i = 0; i < FB_Q; ++i) {
      float best; int bid;
      const float s0 = fmaf(-2.f, a0[i], nr0);
      best = s0; bid = c0;                      // c0 < c1, visited first
      const float s1 = fmaf(-2.f, a1[i], nr1);
      if (s1 < best) { best = s1; bid = c1; }
#pragma unroll
      for (int off = 32; off > 0; off >>= 1) {
        const float s2 = __shfl_down(best, off, 64);
        const int   b2 = __shfl_down(bid, off, 64);
        if (s2 < best || (s2 == best && b2 < bid)) { best = s2; bid = b2; }
      }
      if (lane == 0) { s_best[wv][i] = best; s_bid[wv][i] = bid; }
    }
    __syncthreads();
    if (tid < FB_Q) {   // merge 4 waves, ascending wv = ascending code range
      float best = s_best[0][tid]; int bid = s_bid[0][tid];
#pragma unroll
      for (int w = 1; w < 4; ++w) {
        const float s = s_best[w][tid];
        if (s < best) { best = s; bid = s_bid[w][tid]; }  // tie keeps lower k
      }
      idf[s_qidx[tid]] = (float)bid;
    }
  }
}

// ---------------------------------------------------------------------------
// Gather: q = et[id] (exact fp32 rows), write q_st, diff partials.
// ---------------------------------------------------------------------------
__global__ __launch_bounds__(256) void vq_gather_kernel(
    const float* __restrict__ x, const float* __restrict__ et,
    const float* __restrict__ idf, float* __restrict__ q,
    float* __restrict__ partial)
{
  const int tid = blockIdx.x * 256 + threadIdx.x;
  const int stride = gridDim.x * 256;
  float acc = 0.f;
  for (int idx = tid; idx < N_VEC * (D / 4); idx += stride) {
    const int v = idx >> 4;
    const int d4 = idx & 15;
    const int id = (int)idf[v];
    const float4 xv = reinterpret_cast<const float4*>(x)[idx];
    const float4 ev = reinterpret_cast<const float4*>(et)[(id << 4) + d4];
    const float e0 = ev.x - xv.x, e1 = ev.y - xv.y, e2 = ev.z - xv.z, e3 = ev.w - xv.w;
    acc += (e0 * e0 + e1 * e1) + (e2 * e2 + e3 * e3);
    reinterpret_cast<float4*>(q)[idx] = ev;
  }
  acc += __shfl_down(acc, 32, 64);
  acc += __shfl_down(acc, 16, 64);
  acc += __shfl_down(acc, 8, 64);
  acc += __shfl_down(acc, 4, 64);
  acc += __shfl_down(acc, 2, 64);
  acc += __shfl_down(acc, 1, 64);
  __shared__ float sred[4];
  if ((threadIdx.x & 63) == 0) sred[threadIdx.x >> 6] = acc;
  __syncthreads();
  if (threadIdx.x == 0)
    partial[blockIdx.x] = (sred[0] + sred[1]) + (sred[2] + sred[3]);
}

__global__ __launch_bounds__(256) void vq_finalize_kernel(
    const float* __restrict__ partial, float* __restrict__ out)
{
  float acc = 0.f;
  for (int i = threadIdx.x; i < NB_GATHER; i += 256) acc += partial[i];
  acc += __shfl_down(acc, 32, 64);
  acc += __shfl_down(acc, 16, 64);
  acc += __shfl_down(acc, 8, 64);
  acc += __shfl_down(acc, 4, 64);
  acc += __shfl_down(acc, 2, 64);
  acc += __shfl_down(acc, 1, 64);
  __shared__ float sred[4];
  if ((threadIdx.x & 63) == 0) sred[threadIdx.x >> 6] = acc;
  __syncthreads();
  if (threadIdx.x == 0)
    out[0] = ((sred[0] + sred[1]) + (sred[2] + sred[3])) * (1.0f / (float)(N_VEC * D));
}

extern "C" void kernel_launch(void* const* d_in, const int* in_sizes, int n_in,
                              void* d_out, int out_size, void* d_ws, size_t ws_size,
                              hipStream_t stream) {
  const float* x = (const float*)d_in[0];
  const float* embed = (const float*)d_in[1];
  float* out = (float*)d_out;
  float* q    = out;                 // [0, 8388608): q_st
  float* diff = out + 8388608;       // commitment loss scalar
  float* idf  = out + 8388609;       // emd_id as float [131072]

  float* ws = (float*)d_ws;          // layout (float idx):
  float* et      = ws;               // [0, 32768)       fp32 codebook rows
  float* nrm     = ws + 32768;       // [32768, 33312)   512 norms + 32 pad
  float* partial = ws + 33312;       // [33312, 35360)   diff partials
  int*   cnt     = (int*)(ws + 35360);         // flag counter
  int*   list    = (int*)(ws + 35368);         // flagged query indices
  bf16x8* F = (bf16x8*)(ws + 35368 + N_VEC);   // 128 KB packed hi/mid B-frags

  vq_prep_kernel<<<40, 64, 0, stream>>>(embed, et, nrm, F, cnt);
  vq_coarse_kernel<<<N_VEC / 256, 512, 0, stream>>>(x, F, nrm, idf, cnt, list);
  vq_fallback_kernel<<<1024, 256, 0, stream>>>(x, embed, nrm, cnt, list, idf);
  vq_gather_kernel<<<NB_GATHER, 256, 0, stream>>>(x, et, idf, q, partial);
  vq_finalize_kernel<<<1, 256, 0, stream>>>(partial, diff);
}